// Round 1
// baseline (3609.141 us; speedup 1.0000x reference)
//
#include <hip/hip_runtime.h>
#include <hip/hip_bf16.h>
#include <math.h>

// DistributedAFNO2D: out = x + irfft2( blockMLP( rfft2(x, ortho) ), ortho )
// B=2, C=768, H=W=256, 8 blocks x 96 ch, KW = 129 frequency cols.
// Frequency buffer F in d_ws: bf16-packed complex (u32 = [imag:bf16 | real:bf16]),
// layout (B*C, KW, H) so H is contiguous -> column FFT + mix are coalesced.

#define LAMBDA_SS 0.01f

typedef unsigned int u32;

__device__ __forceinline__ u32 pack_bf16(float r, float i) {
  union { float f; u32 u; } ur, ui;
  ur.f = r; ui.f = i;
  u32 rb = (ur.u + 0x7FFFu + ((ur.u >> 16) & 1u)) >> 16;
  u32 ib = (ui.u + 0x7FFFu + ((ui.u >> 16) & 1u)) >> 16;
  return (ib << 16) | (rb & 0xFFFFu);
}

__device__ __forceinline__ float2 unpack_bf16(u32 p) {
  union { u32 u; float f; } a, b;
  a.u = (p & 0xFFFFu) << 16;
  b.u = (p & 0xFFFF0000u);
  return make_float2(a.f, b.f);
}

// tw[k] = exp(-2*pi*i*k/256), k = 0..127
__device__ __forceinline__ void init_tw(float2* tw, int tid) {
  if (tid < 128) {
    float ang = -2.0f * 3.14159265358979323846f * (float)tid / 256.0f;
    tw[tid] = make_float2(cosf(ang), sinf(ang));
  }
}

// In-place 256-pt radix-2 DIT FFT on one wave's LDS buffer w[256].
// Input must be pre-scattered in bit-reversed order. isign=+1 fwd, -1 inv.
// Contains __syncthreads: every wave in the block must call uniformly.
__device__ __forceinline__ void fft256(float2* w, const float2* tw, int lane, float isign) {
#pragma unroll
  for (int len = 2; len <= 256; len <<= 1) {
    const int half = len >> 1;
    const int tmul = 256 / len;
#pragma unroll
    for (int jj = 0; jj < 2; ++jj) {
      int j = lane + 64 * jj;          // 128 butterflies, 2 per lane
      int grp = j / half;
      int t = j - grp * half;
      int i0 = grp * len + t;
      int i1 = i0 + half;
      float2 W = tw[t * tmul];
      float wr = W.x, wi = isign * W.y;
      float2 u = w[i0], v = w[i1];
      float vr = v.x * wr - v.y * wi;
      float vi = v.x * wi + v.y * wr;
      w[i0] = make_float2(u.x + vr, u.y + vi);
      w[i1] = make_float2(u.x - vr, u.y - vi);
    }
    __syncthreads();
  }
}

// ---------------- Pass 1: row rfft (W axis), write (bc, kw, h) bf16 ----------------
__global__ __launch_bounds__(256) void k_rowfft(const float* __restrict__ x, u32* __restrict__ F) {
  __shared__ float2 work[4][256];
  __shared__ float2 tw[128];
  __shared__ u32 stage[129 * 65];   // [kw][h_local], padded to kill bank conflicts

  const int bc = blockIdx.x >> 2;   // b*768 + c
  const int hc = blockIdx.x & 3;    // 64-row chunk
  const int tid = threadIdx.x;
  const int wave = tid >> 6, lane = tid & 63;
  init_tw(tw, tid);
  __syncthreads();

  float2* w = work[wave];
  for (int r = 0; r < 16; ++r) {
    const int hl = wave * 16 + r;
    const int h = hc * 64 + hl;
    float4 xv = reinterpret_cast<const float4*>(x + ((size_t)bc * 256 + h) * 256)[lane];
    const int i0 = 4 * lane;
    w[__brev(i0 + 0) >> 24] = make_float2(xv.x, 0.f);
    w[__brev(i0 + 1) >> 24] = make_float2(xv.y, 0.f);
    w[__brev(i0 + 2) >> 24] = make_float2(xv.z, 0.f);
    w[__brev(i0 + 3) >> 24] = make_float2(xv.w, 0.f);
    __syncthreads();
    fft256(w, tw, lane, 1.f);
    // keep kw = 0..128 (no normalization here; 1/256 applied in column FFT)
    stage[lane * 65 + hl]        = pack_bf16(w[lane].x, w[lane].y);
    stage[(lane + 64) * 65 + hl] = pack_bf16(w[lane + 64].x, w[lane + 64].y);
    if (lane == 0) stage[128 * 65 + hl] = pack_bf16(w[128].x, w[128].y);
    __syncthreads();
  }
  // coalesced write-out: for each kw, 64 consecutive h (256B)
  for (int idx = tid; idx < 129 * 64; idx += 256) {
    const int kw = idx >> 6, hl = idx & 63;
    F[((size_t)bc * 129 + kw) * 256 + hc * 64 + hl] = stage[kw * 65 + hl];
  }
}

// ---------------- Pass 2/4: column FFT (H axis) in place, scale 1/256 ----------------
__global__ __launch_bounds__(256) void k_colfft(u32* __restrict__ F, float isign) {
  __shared__ float2 work[4][256];
  __shared__ float2 tw[128];
  const int tid = threadIdx.x, wave = tid >> 6, lane = tid & 63;
  init_tw(tw, tid);
  __syncthreads();

  const size_t col = (size_t)blockIdx.x * 4 + wave;   // bc*129 + kw  (< 198144)
  float2* w = work[wave];
  uint4 pv = reinterpret_cast<const uint4*>(F + col * 256)[lane];
  const int i0 = 4 * lane;
  w[__brev(i0 + 0) >> 24] = unpack_bf16(pv.x);
  w[__brev(i0 + 1) >> 24] = unpack_bf16(pv.y);
  w[__brev(i0 + 2) >> 24] = unpack_bf16(pv.z);
  w[__brev(i0 + 3) >> 24] = unpack_bf16(pv.w);
  __syncthreads();
  fft256(w, tw, lane, isign);
  const float s = 1.0f / 256.0f;     // ortho: 1/sqrt(H*W) fwd, 1/sqrt(H*W) inv
  uint4 ov;
  float2 a;
  a = w[i0 + 0]; ov.x = pack_bf16(a.x * s, a.y * s);
  a = w[i0 + 1]; ov.y = pack_bf16(a.x * s, a.y * s);
  a = w[i0 + 2]; ov.z = pack_bf16(a.x * s, a.y * s);
  a = w[i0 + 3]; ov.w = pack_bf16(a.x * s, a.y * s);
  reinterpret_cast<uint4*>(F + col * 256)[lane] = ov;
}

// ---------------- Pass 3: per-site block MLP (complex 96->96->96) in place ----------------
__global__ __launch_bounds__(256) void k_mix(u32* __restrict__ F,
    const float2* __restrict__ w1, const float2* __restrict__ b1,
    const float2* __restrict__ w2, const float2* __restrict__ b2) {
  __shared__ u32 O1[96 * 64];   // [o][h] bf16-packed

  const int bi = blockIdx.x;
  const int hc = bi & 3;
  const int kw = (bi >> 2) % 129;
  const int bk = (bi >> 2) / 129;   // b*8 + k
  const int k = bk & 7, b = bk >> 3;
  const int tid = threadIdx.x;
  const int h = tid & 63, og = tid >> 6;   // 4 output groups x 24 outputs

  const size_t stride_i = 129 * 256;
  const size_t base = (((size_t)b * 768 + (size_t)k * 96) * 129 + kw) * 256 + hc * 64 + h;

  float accr[24], acci[24];
#pragma unroll
  for (int j = 0; j < 24; ++j) { accr[j] = 0.f; acci[j] = 0.f; }

  const float2* w1k = w1 + (size_t)k * 96 * 96;
  for (int i = 0; i < 96; ++i) {
    float2 a = unpack_bf16(F[base + (size_t)i * stride_i]);
    const float2* wrow = w1k + i * 96 + og * 24;
#pragma unroll
    for (int j = 0; j < 24; ++j) {
      float2 W = wrow[j];
      accr[j] = fmaf(a.x, W.x, fmaf(-a.y, W.y, accr[j]));
      acci[j] = fmaf(a.y, W.x, fmaf(a.x, W.y, acci[j]));
    }
  }
#pragma unroll
  for (int j = 0; j < 24; ++j) {
    const int o = og * 24 + j;
    float2 bb = b1[k * 96 + o];
    float r  = fmaxf(accr[j] + bb.x, 0.f);
    float im = fmaxf(acci[j] + bb.y, 0.f);
    O1[o * 64 + h] = pack_bf16(r, im);
  }
  __syncthreads();

#pragma unroll
  for (int j = 0; j < 24; ++j) { accr[j] = 0.f; acci[j] = 0.f; }
  const float2* w2k = w2 + (size_t)k * 96 * 96;
  for (int i = 0; i < 96; ++i) {
    float2 a = unpack_bf16(O1[i * 64 + h]);
    const float2* wrow = w2k + i * 96 + og * 24;
#pragma unroll
    for (int j = 0; j < 24; ++j) {
      float2 W = wrow[j];
      accr[j] = fmaf(a.x, W.x, fmaf(-a.y, W.y, accr[j]));
      acci[j] = fmaf(a.y, W.x, fmaf(a.x, W.y, acci[j]));
    }
  }
#pragma unroll
  for (int j = 0; j < 24; ++j) {
    const int o = og * 24 + j;
    float2 bb = b2[k * 96 + o];
    float r  = accr[j] + bb.x;
    float im = acci[j] + bb.y;
    r  = (r  >  LAMBDA_SS) ? r  - LAMBDA_SS : ((r  < -LAMBDA_SS) ? r  + LAMBDA_SS : 0.f);
    im = (im >  LAMBDA_SS) ? im - LAMBDA_SS : ((im < -LAMBDA_SS) ? im + LAMBDA_SS : 0.f);
    F[base + (size_t)o * stride_i] = pack_bf16(r, im);
  }
}

// ---------------- Pass 5: row irfft (Hermitian extension) + bias add ----------------
__global__ __launch_bounds__(256) void k_rowifft(const u32* __restrict__ F,
                                                 const float* __restrict__ x,
                                                 float* __restrict__ out) {
  __shared__ float2 work[4][256];
  __shared__ float2 tw[128];
  __shared__ u32 stage[129 * 65];

  const int bc = blockIdx.x >> 2, hc = blockIdx.x & 3;
  const int tid = threadIdx.x, wave = tid >> 6, lane = tid & 63;
  init_tw(tw, tid);
  for (int idx = tid; idx < 129 * 64; idx += 256) {
    const int kw = idx >> 6, hl = idx & 63;
    stage[kw * 65 + hl] = F[((size_t)bc * 129 + kw) * 256 + hc * 64 + hl];
  }
  __syncthreads();

  float2* w = work[wave];
  for (int r = 0; r < 16; ++r) {
    const int hl = wave * 16 + r;
    const int h = hc * 64 + hl;
#pragma unroll
    for (int m = 0; m < 4; ++m) {
      const int kw = lane + 64 * m;                 // 0..255
      const int src = (kw <= 128) ? kw : 256 - kw;  // Hermitian extension
      float2 v = unpack_bf16(stage[src * 65 + hl]);
      if (kw > 128) v.y = -v.y;
      w[__brev(kw) >> 24] = v;
    }
    __syncthreads();
    fft256(w, tw, lane, -1.f);   // inverse; 1/256 already applied in column IFFT
    float4 xv = reinterpret_cast<const float4*>(x + ((size_t)bc * 256 + h) * 256)[lane];
    const int i0 = 4 * lane;
    float4 ov;
    ov.x = w[i0 + 0].x + xv.x;
    ov.y = w[i0 + 1].x + xv.y;
    ov.z = w[i0 + 2].x + xv.z;
    ov.w = w[i0 + 3].x + xv.w;
    reinterpret_cast<float4*>(out + ((size_t)bc * 256 + h) * 256)[lane] = ov;
    __syncthreads();
  }
}

extern "C" void kernel_launch(void* const* d_in, const int* in_sizes, int n_in,
                              void* d_out, int out_size, void* d_ws, size_t ws_size,
                              hipStream_t stream) {
  const float* x  = (const float*)d_in[0];
  const float2* w1 = (const float2*)d_in[1];
  const float2* b1 = (const float2*)d_in[2];
  const float2* w2 = (const float2*)d_in[3];
  const float2* b2 = (const float2*)d_in[4];
  float* out = (float*)d_out;
  u32* F = (u32*)d_ws;   // needs 1536*129*256*4 B = ~203 MB of scratch

  const int n_rows_blocks = 1536 * 4;          // (B*C) x 4 chunks of 64 rows
  const int n_cols_blocks = (1536 * 129) / 4;  // 4 columns (waves) per block
  const int n_mix_blocks  = 2 * 8 * 129 * 4;   // b x k x kw x h-chunk64

  k_rowfft<<<n_rows_blocks, 256, 0, stream>>>(x, F);
  k_colfft<<<n_cols_blocks, 256, 0, stream>>>(F, 1.f);
  k_mix<<<n_mix_blocks, 256, 0, stream>>>(F, w1, b1, w2, b2);
  k_colfft<<<n_cols_blocks, 256, 0, stream>>>(F, -1.f);
  k_rowifft<<<n_rows_blocks, 256, 0, stream>>>(F, x, out);
}

// Round 2
// 1597.617 us; speedup vs baseline: 2.2591x; 2.2591x over previous
//
#include <hip/hip_runtime.h>
#include <hip/hip_bf16.h>
#include <math.h>

// DistributedAFNO2D: out = x + irfft2( blockMLP( rfft2(x, ortho) ), ortho )
// B=2, C=768, H=W=256, 8 blocks x 96 ch, KW = 129 frequency cols.
// F in d_ws: bf16-packed complex (u32 = [imag:bf16 | real:bf16]), layout (B*C, KW, H).
// Mix pass = MFMA GEMM: C(192 x sites) = Amat(192x192) x Bdata(192 x sites) per (b,k),
// complex expanded with interleaved real/imag (k-index 2i=real, 2i+1=imag).

#define LAMBDA_SS 0.01f

typedef unsigned int u32;
typedef __attribute__((ext_vector_type(8))) short bf16x8;
typedef __attribute__((ext_vector_type(4))) float f32x4;

__device__ __forceinline__ u32 pack_bf16(float r, float i) {
  union { float f; u32 u; } ur, ui;
  ur.f = r; ui.f = i;
  u32 rb = (ur.u + 0x7FFFu + ((ur.u >> 16) & 1u)) >> 16;
  u32 ib = (ui.u + 0x7FFFu + ((ui.u >> 16) & 1u)) >> 16;
  return (ib << 16) | (rb & 0xFFFFu);
}

__device__ __forceinline__ float2 unpack_bf16(u32 p) {
  union { u32 u; float f; } a, b;
  a.u = (p & 0xFFFFu) << 16;
  b.u = (p & 0xFFFF0000u);
  return make_float2(a.f, b.f);
}

__device__ __forceinline__ float sshrink(float v) {
  return (v > LAMBDA_SS) ? v - LAMBDA_SS : ((v < -LAMBDA_SS) ? v + LAMBDA_SS : 0.f);
}

// tw[k] = exp(-2*pi*i*k/256), k = 0..127
__device__ __forceinline__ void init_tw(float2* tw, int tid) {
  if (tid < 128) {
    float ang = -2.0f * 3.14159265358979323846f * (float)tid / 256.0f;
    tw[tid] = make_float2(cosf(ang), sinf(ang));
  }
}

// In-place 256-pt radix-2 DIT FFT on one wave's LDS buffer w[256].
__device__ __forceinline__ void fft256(float2* w, const float2* tw, int lane, float isign) {
#pragma unroll
  for (int len = 2; len <= 256; len <<= 1) {
    const int half = len >> 1;
    const int tmul = 256 / len;
#pragma unroll
    for (int jj = 0; jj < 2; ++jj) {
      int j = lane + 64 * jj;
      int grp = j / half;
      int t = j - grp * half;
      int i0 = grp * len + t;
      int i1 = i0 + half;
      float2 W = tw[t * tmul];
      float wr = W.x, wi = isign * W.y;
      float2 u = w[i0], v = w[i1];
      float vr = v.x * wr - v.y * wi;
      float vi = v.x * wi + v.y * wr;
      w[i0] = make_float2(u.x + vr, u.y + vi);
      w[i1] = make_float2(u.x - vr, u.y - vi);
    }
    __syncthreads();
  }
}

// ---------------- Pass 1: row rfft (W axis), write (bc, kw, h) bf16 ----------------
__global__ __launch_bounds__(256) void k_rowfft(const float* __restrict__ x, u32* __restrict__ F) {
  __shared__ float2 work[4][256];
  __shared__ float2 tw[128];
  __shared__ u32 stage[129 * 65];

  const int bc = blockIdx.x >> 2;
  const int hc = blockIdx.x & 3;
  const int tid = threadIdx.x;
  const int wave = tid >> 6, lane = tid & 63;
  init_tw(tw, tid);
  __syncthreads();

  float2* w = work[wave];
  for (int r = 0; r < 16; ++r) {
    const int hl = wave * 16 + r;
    const int h = hc * 64 + hl;
    float4 xv = reinterpret_cast<const float4*>(x + ((size_t)bc * 256 + h) * 256)[lane];
    const int i0 = 4 * lane;
    w[__brev(i0 + 0) >> 24] = make_float2(xv.x, 0.f);
    w[__brev(i0 + 1) >> 24] = make_float2(xv.y, 0.f);
    w[__brev(i0 + 2) >> 24] = make_float2(xv.z, 0.f);
    w[__brev(i0 + 3) >> 24] = make_float2(xv.w, 0.f);
    __syncthreads();
    fft256(w, tw, lane, 1.f);
    stage[lane * 65 + hl]        = pack_bf16(w[lane].x, w[lane].y);
    stage[(lane + 64) * 65 + hl] = pack_bf16(w[lane + 64].x, w[lane + 64].y);
    if (lane == 0) stage[128 * 65 + hl] = pack_bf16(w[128].x, w[128].y);
    __syncthreads();
  }
  for (int idx = tid; idx < 129 * 64; idx += 256) {
    const int kw = idx >> 6, hl = idx & 63;
    F[((size_t)bc * 129 + kw) * 256 + hc * 64 + hl] = stage[kw * 65 + hl];
  }
}

// ---------------- Pass 2/4: column FFT (H axis) in place, scale 1/256 ----------------
__global__ __launch_bounds__(256) void k_colfft(u32* __restrict__ F, float isign) {
  __shared__ float2 work[4][256];
  __shared__ float2 tw[128];
  const int tid = threadIdx.x, wave = tid >> 6, lane = tid & 63;
  init_tw(tw, tid);
  __syncthreads();

  const size_t col = (size_t)blockIdx.x * 4 + wave;
  float2* w = work[wave];
  uint4 pv = reinterpret_cast<const uint4*>(F + col * 256)[lane];
  const int i0 = 4 * lane;
  w[__brev(i0 + 0) >> 24] = unpack_bf16(pv.x);
  w[__brev(i0 + 1) >> 24] = unpack_bf16(pv.y);
  w[__brev(i0 + 2) >> 24] = unpack_bf16(pv.z);
  w[__brev(i0 + 3) >> 24] = unpack_bf16(pv.w);
  __syncthreads();
  fft256(w, tw, lane, isign);
  const float s = 1.0f / 256.0f;
  uint4 ov;
  float2 a;
  a = w[i0 + 0]; ov.x = pack_bf16(a.x * s, a.y * s);
  a = w[i0 + 1]; ov.y = pack_bf16(a.x * s, a.y * s);
  a = w[i0 + 2]; ov.z = pack_bf16(a.x * s, a.y * s);
  a = w[i0 + 3]; ov.w = pack_bf16(a.x * s, a.y * s);
  reinterpret_cast<uint4*>(F + col * 256)[lane] = ov;
}

// ---------------- Weight prep: expand complex W into interleaved real Amat (bf16) ----
// Amat[m][kk], m = 2o(+1), kk = 2i(+1):
//   [2o][2i]=Wr[i][o], [2o][2i+1]=-Wi[i][o], [2o+1][2i]=Wi[i][o], [2o+1][2i+1]=Wr[i][o]
// Stored as u32 (pair of bf16 along kk): Wt32[(k*2+layer)*18432 + m*96 + i]
__global__ __launch_bounds__(256) void k_prep_w(const float2* __restrict__ w1,
                                                const float2* __restrict__ w2,
                                                u32* __restrict__ Wt) {
  const int blk = blockIdx.x;      // k*2 + layer
  const int k = blk >> 1, layer = blk & 1;
  const float2* w = (layer == 0 ? w1 : w2) + (size_t)k * 96 * 96;
  u32* out = Wt + (size_t)blk * 18432;
  for (int idx = threadIdx.x; idx < 9216; idx += 256) {
    int o = idx % 96, i = idx / 96;
    float2 v = w[i * 96 + o];
    out[(2 * o) * 96 + i]     = pack_bf16(v.x, -v.y);
    out[(2 * o + 1) * 96 + i] = pack_bf16(v.y, v.x);
  }
}

// ---------------- Pass 3: MFMA block-MLP, in place on F ----------------
// Block: 512 thr (8 waves, 2M x 4N), tile M=192, N=128 sites, K=192.
// LDS: Wlds [192][192] bf16 (73728 B) + Dlds [128][192] bf16 (49152 B), XOR-swizzled.
#define MIX_LDS_BYTES (73728 + 49152)

__global__ __launch_bounds__(512) void k_mix_mfma(u32* __restrict__ F,
    const u32* __restrict__ Wt,
    const float2* __restrict__ b1, const float2* __restrict__ b2) {
  extern __shared__ char smem[];
  char* Wlds = smem;            // 73728 B
  char* Dlds = smem + 73728;    // 49152 B

  const int bi = blockIdx.x;
  const int hc = bi & 1;
  const int kw = (bi >> 1) % 129;
  const int bk = (bi >> 1) / 129;
  const int k = bk & 7, b = bk >> 3;
  const int t = threadIdx.x;
  const int lane = t & 63, wave = t >> 6;
  const int wm = wave >> 2, wn = wave & 3;     // m0 = wm*96, n0 = wn*32
  const int lrow = lane & 15;
  const int lk = (lane >> 4) * 16;             // k byte offset within k-step

  const u32* W1g = Wt + (size_t)(k * 2 + 0) * 18432;
  const u32* W2g = Wt + (size_t)(k * 2 + 1) * 18432;

  // ---- stage W1 into Wlds (16B chunks, swizzled) ----
#pragma unroll
  for (int c = 0; c < 9; ++c) {
    int idx = c * 512 + t;           // of 4608 chunks
    int byte = idx * 16;
    int row = idx / 24;              // 24 chunks per 384B row
    uint4 v = reinterpret_cast<const uint4*>(W1g)[idx];
    *reinterpret_cast<uint4*>(Wlds + (byte ^ ((row & 7) << 4))) = v;
  }

  // ---- stage data tile into Dlds: Dlds[h][2i]=real, [2i+1]=imag (u32 pair) ----
  const size_t chstride = 129 * 256;
  const size_t base = (((size_t)(b * 768 + k * 96)) * 129 + kw) * 256 + (size_t)hc * 128;
  {
    const int h = t & 127;
    const int pg = t >> 7;           // 0..3
#pragma unroll
    for (int it = 0; it < 12; ++it) {
      int p = it * 4 + pg;           // channel pair 0..47
      u32 a0 = F[base + (size_t)(2 * p) * chstride + h];
      u32 a1 = F[base + (size_t)(2 * p + 1) * chstride + h];
      int byte = h * 384 + p * 8;
      *reinterpret_cast<uint2*>(Dlds + (byte ^ ((h & 7) << 4))) = make_uint2(a0, a1);
    }
  }

  // ---- issue W2 loads early (land during layer-1 compute) ----
  uint4 w2buf[9];
#pragma unroll
  for (int c = 0; c < 9; ++c) w2buf[c] = reinterpret_cast<const uint4*>(W2g)[c * 512 + t];

  __syncthreads();

  // ---- layer 1: acc[mi][ni] over 6 k-steps ----
  f32x4 acc[6][2];
#pragma unroll
  for (int mi = 0; mi < 6; ++mi)
#pragma unroll
    for (int ni = 0; ni < 2; ++ni) acc[mi][ni] = (f32x4)0.f;

#pragma unroll
  for (int ks = 0; ks < 6; ++ks) {
    const int kb = ks * 64;          // k-step byte offset (32 elems * 2B)
    bf16x8 afrag[6];
#pragma unroll
    for (int mi = 0; mi < 6; ++mi) {
      int row = wm * 96 + mi * 16 + lrow;
      int byte = row * 384 + kb + lk;
      afrag[mi] = *reinterpret_cast<bf16x8*>(Wlds + (byte ^ ((row & 7) << 4)));
    }
#pragma unroll
    for (int ni = 0; ni < 2; ++ni) {
      int row = wn * 32 + ni * 16 + lrow;
      int byte = row * 384 + kb + lk;
      bf16x8 bfrag = *reinterpret_cast<bf16x8*>(Dlds + (byte ^ ((row & 7) << 4)));
#pragma unroll
      for (int mi = 0; mi < 6; ++mi)
        acc[mi][ni] = __builtin_amdgcn_mfma_f32_16x16x32_bf16(afrag[mi], bfrag, acc[mi][ni], 0, 0, 0);
    }
  }
  __syncthreads();   // all W1/Dlds reads done

  // ---- stage W2 into Wlds; write O1 (bias1 + ReLU, bf16) into Dlds ----
#pragma unroll
  for (int c = 0; c < 9; ++c) {
    int idx = c * 512 + t;
    int byte = idx * 16;
    int row = idx / 24;
    *reinterpret_cast<uint4*>(Wlds + (byte ^ ((row & 7) << 4))) = w2buf[c];
  }
  const float2* b1k = b1 + k * 96;
#pragma unroll
  for (int mi = 0; mi < 6; ++mi) {
    int m0 = wm * 96 + mi * 16 + 4 * (lane >> 4);   // multiple of 4
    int o0 = m0 >> 1;
    float2 ba = b1k[o0], bb = b1k[o0 + 1];
#pragma unroll
    for (int ni = 0; ni < 2; ++ni) {
      int n = wn * 32 + ni * 16 + lrow;
      f32x4 v = acc[mi][ni];
      u32 lo  = pack_bf16(fmaxf(v[0] + ba.x, 0.f), fmaxf(v[1] + ba.y, 0.f));
      u32 hi  = pack_bf16(fmaxf(v[2] + bb.x, 0.f), fmaxf(v[3] + bb.y, 0.f));
      int byte = n * 384 + m0 * 2;
      *reinterpret_cast<uint2*>(Dlds + (byte ^ ((n & 7) << 4))) = make_uint2(lo, hi);
    }
  }
  __syncthreads();

  // ---- layer 2 ----
#pragma unroll
  for (int mi = 0; mi < 6; ++mi)
#pragma unroll
    for (int ni = 0; ni < 2; ++ni) acc[mi][ni] = (f32x4)0.f;

#pragma unroll
  for (int ks = 0; ks < 6; ++ks) {
    const int kb = ks * 64;
    bf16x8 afrag[6];
#pragma unroll
    for (int mi = 0; mi < 6; ++mi) {
      int row = wm * 96 + mi * 16 + lrow;
      int byte = row * 384 + kb + lk;
      afrag[mi] = *reinterpret_cast<bf16x8*>(Wlds + (byte ^ ((row & 7) << 4)));
    }
#pragma unroll
    for (int ni = 0; ni < 2; ++ni) {
      int row = wn * 32 + ni * 16 + lrow;
      int byte = row * 384 + kb + lk;
      bf16x8 bfrag = *reinterpret_cast<bf16x8*>(Dlds + (byte ^ ((row & 7) << 4)));
#pragma unroll
      for (int mi = 0; mi < 6; ++mi)
        acc[mi][ni] = __builtin_amdgcn_mfma_f32_16x16x32_bf16(afrag[mi], bfrag, acc[mi][ni], 0, 0, 0);
    }
  }

  // ---- epilogue: bias2 + softshrink, write F in place ----
  const float2* b2k = b2 + k * 96;
#pragma unroll
  for (int mi = 0; mi < 6; ++mi) {
    int m0 = wm * 96 + mi * 16 + 4 * (lane >> 4);
    int o0 = m0 >> 1;
    float2 ca = b2k[o0], cb = b2k[o0 + 1];
#pragma unroll
    for (int ni = 0; ni < 2; ++ni) {
      int n = wn * 32 + ni * 16 + lrow;
      f32x4 v = acc[mi][ni];
      u32 lo = pack_bf16(sshrink(v[0] + ca.x), sshrink(v[1] + ca.y));
      u32 hi = pack_bf16(sshrink(v[2] + cb.x), sshrink(v[3] + cb.y));
      F[base + (size_t)o0 * chstride + n]       = lo;
      F[base + (size_t)(o0 + 1) * chstride + n] = hi;
    }
  }
}

// ---------------- Pass 5: row irfft (Hermitian extension) + bias add ----------------
__global__ __launch_bounds__(256) void k_rowifft(const u32* __restrict__ F,
                                                 const float* __restrict__ x,
                                                 float* __restrict__ out) {
  __shared__ float2 work[4][256];
  __shared__ float2 tw[128];
  __shared__ u32 stage[129 * 65];

  const int bc = blockIdx.x >> 2, hc = blockIdx.x & 3;
  const int tid = threadIdx.x, wave = tid >> 6, lane = tid & 63;
  init_tw(tw, tid);
  for (int idx = tid; idx < 129 * 64; idx += 256) {
    const int kw = idx >> 6, hl = idx & 63;
    stage[kw * 65 + hl] = F[((size_t)bc * 129 + kw) * 256 + hc * 64 + hl];
  }
  __syncthreads();

  float2* w = work[wave];
  for (int r = 0; r < 16; ++r) {
    const int hl = wave * 16 + r;
    const int h = hc * 64 + hl;
#pragma unroll
    for (int m = 0; m < 4; ++m) {
      const int kw = lane + 64 * m;
      const int src = (kw <= 128) ? kw : 256 - kw;
      float2 v = unpack_bf16(stage[src * 65 + hl]);
      if (kw > 128) v.y = -v.y;
      w[__brev(kw) >> 24] = v;
    }
    __syncthreads();
    fft256(w, tw, lane, -1.f);
    float4 xv = reinterpret_cast<const float4*>(x + ((size_t)bc * 256 + h) * 256)[lane];
    const int i0 = 4 * lane;
    float4 ov;
    ov.x = w[i0 + 0].x + xv.x;
    ov.y = w[i0 + 1].x + xv.y;
    ov.z = w[i0 + 2].x + xv.z;
    ov.w = w[i0 + 3].x + xv.w;
    reinterpret_cast<float4*>(out + ((size_t)bc * 256 + h) * 256)[lane] = ov;
    __syncthreads();
  }
}

extern "C" void kernel_launch(void* const* d_in, const int* in_sizes, int n_in,
                              void* d_out, int out_size, void* d_ws, size_t ws_size,
                              hipStream_t stream) {
  const float* x   = (const float*)d_in[0];
  const float2* w1 = (const float2*)d_in[1];
  const float2* b1 = (const float2*)d_in[2];
  const float2* w2 = (const float2*)d_in[3];
  const float2* b2 = (const float2*)d_in[4];
  float* out = (float*)d_out;
  u32* F = (u32*)d_ws;            // 1536*129*256*4 B ~ 203 MB
  u32* Wt = (u32*)d_out;          // d_out head as scratch (1.18 MB); fully
                                  // overwritten by k_rowifft at the end.

  (void)hipFuncSetAttribute(reinterpret_cast<const void*>(k_mix_mfma),
                            hipFuncAttributeMaxDynamicSharedMemorySize, MIX_LDS_BYTES);

  const int n_rows_blocks = 1536 * 4;
  const int n_cols_blocks = (1536 * 129) / 4;
  const int n_mix_blocks  = 2 * 8 * 129 * 2;   // b x k x kw x (2 half-rows of 128 sites)

  k_prep_w<<<16, 256, 0, stream>>>(w1, w2, Wt);
  k_rowfft<<<n_rows_blocks, 256, 0, stream>>>(x, F);
  k_colfft<<<n_cols_blocks, 256, 0, stream>>>(F, 1.f);
  k_mix_mfma<<<n_mix_blocks, 512, MIX_LDS_BYTES, stream>>>(F, Wt, b1, b2);
  k_colfft<<<n_cols_blocks, 256, 0, stream>>>(F, -1.f);
  k_rowifft<<<n_rows_blocks, 256, 0, stream>>>(F, x, out);
}

// Round 3
// 886.105 us; speedup vs baseline: 4.0730x; 1.8030x over previous
//
#include <hip/hip_runtime.h>
#include <hip/hip_bf16.h>
#include <math.h>

// DistributedAFNO2D: out = x + irfft2( blockMLP( rfft2(x, ortho) ), ortho )
// B=2, C=768, H=W=256, 8 blocks x 96 ch, KW = 129 frequency cols.
// F in d_ws: bf16-packed complex (u32 = [imag:bf16 | real:bf16]), layout (B*C, KW, H).
// H axis of F holds the column spectrum in BIT-REVERSED order (mix is pointwise,
// so the permutation is free; inverse DIT consumes it natively).
// All FFTs are register-resident: 4 complex/lane, exchanges via shfl_xor.

#define LAMBDA_SS 0.01f

typedef unsigned int u32;
typedef __attribute__((ext_vector_type(8))) short bf16x8;
typedef __attribute__((ext_vector_type(4))) float f32x4;

__device__ __forceinline__ u32 pack_bf16(float r, float i) {
  union { float f; u32 u; } ur, ui;
  ur.f = r; ui.f = i;
  u32 rb = (ur.u + 0x7FFFu + ((ur.u >> 16) & 1u)) >> 16;
  u32 ib = (ui.u + 0x7FFFu + ((ui.u >> 16) & 1u)) >> 16;
  return (ib << 16) | (rb & 0xFFFFu);
}

__device__ __forceinline__ float2 unpack_bf16(u32 p) {
  union { u32 u; float f; } a, b;
  a.u = (p & 0xFFFFu) << 16;
  b.u = (p & 0xFFFF0000u);
  return make_float2(a.f, b.f);
}

__device__ __forceinline__ float sshrink(float v) {
  return (v > LAMBDA_SS) ? v - LAMBDA_SS : ((v < -LAMBDA_SS) ? v + LAMBDA_SS : 0.f);
}

// ---------------- register FFT machinery ----------------
__device__ __forceinline__ float2 cadd(float2 a, float2 b){ return make_float2(a.x+b.x, a.y+b.y); }
__device__ __forceinline__ float2 csub(float2 a, float2 b){ return make_float2(a.x-b.x, a.y-b.y); }
__device__ __forceinline__ float2 cmul(float2 a, float2 b){
  return make_float2(fmaf(a.x,b.x,-a.y*b.y), fmaf(a.x,b.y,a.y*b.x));
}
// a * (si*i):  si=-1 -> (y,-x);  si=+1 -> (-y,x)
__device__ __forceinline__ float2 cmulj(float2 a, float si){
  return make_float2(-si*a.y, si*a.x);
}
__device__ __forceinline__ float2 shflx(float2 v, int m){
  return make_float2(__shfl_xor(v.x, m, 64), __shfl_xor(v.y, m, 64));
}
__device__ __forceinline__ float2 shfll(float2 v, int l){
  return make_float2(__shfl(v.x, l, 64), __shfl(v.y, l, 64));
}
__device__ __forceinline__ int brev6(int x){ return (int)(__brev((u32)x) >> 26); }

struct Tw { float2 t128, t64, t32, t16, t8, t4; float si; };

// twiddle W^e: exp(si * i * 2*pi*e/256); si=-1 forward, +1 inverse
__device__ __forceinline__ float2 mkTw(int e, float si){
  float a = (float)e * 0.0245436926f;   // 2*pi/256
  return make_float2(cosf(a), si*sinf(a));
}
__device__ __forceinline__ Tw make_tw(int lane, float si){
  Tw w; w.si = si;
  w.t128 = mkTw(lane, si);
  w.t64  = mkTw(2*lane, si);
  w.t32  = mkTw((lane&31)*4, si);
  w.t16  = mkTw((lane&15)*8, si);
  w.t8   = mkTw((lane&7)*16, si);
  w.t4   = mkTw((lane&3)*32, si);
  return w;
}

__device__ __forceinline__ float2 bfly_dif(float2 v, int h, float2 th, int lane){
  float2 p = shflx(v, h);
  float sx = (lane & h) ? -1.f : 1.f;
  float2 s = make_float2(fmaf(sx, v.x, p.x), fmaf(sx, v.y, p.y));
  if (lane & h) s = cmul(s, th);
  return s;
}
__device__ __forceinline__ float2 bfly_dit(float2 v, int h, float2 th, int lane){
  if (lane & h) v = cmul(v, th);
  float2 p = shflx(v, h);
  float sx = (lane & h) ? -1.f : 1.f;
  return make_float2(fmaf(sx, v.x, p.x), fmaf(sx, v.y, p.y));
}

// Forward DIF: natural input at d = lane + 64r; output X[brev8(d)] at slot d.
__device__ __forceinline__ void fft256_dif(float2 v[4], int lane, const Tw& T){
  float2 t128b = cmulj(T.t128, T.si);
  { float2 a=v[0], b=v[2]; v[0]=cadd(a,b); v[2]=cmul(csub(a,b), T.t128);
    float2 c=v[1], d=v[3]; v[1]=cadd(c,d); v[3]=cmul(csub(c,d), t128b); }
  { float2 a=v[0], b=v[1]; v[0]=cadd(a,b); v[1]=cmul(csub(a,b), T.t64);
    float2 c=v[2], d=v[3]; v[2]=cadd(c,d); v[3]=cmul(csub(c,d), T.t64); }
#pragma unroll
  for (int r=0;r<4;++r) v[r]=bfly_dif(v[r],32,T.t32,lane);
#pragma unroll
  for (int r=0;r<4;++r) v[r]=bfly_dif(v[r],16,T.t16,lane);
#pragma unroll
  for (int r=0;r<4;++r) v[r]=bfly_dif(v[r],8,T.t8,lane);
#pragma unroll
  for (int r=0;r<4;++r) v[r]=bfly_dif(v[r],4,T.t4,lane);
#pragma unroll
  for (int r=0;r<4;++r){                       // h=2: tw = W^((lane&1)*64)
    float2 p=shflx(v[r],2);
    float sx=(lane&2)?-1.f:1.f;
    float2 s=make_float2(fmaf(sx,v[r].x,p.x), fmaf(sx,v[r].y,p.y));
    if ((lane&3)==3) s=cmulj(s,T.si);
    v[r]=s;
  }
#pragma unroll
  for (int r=0;r<4;++r){                       // h=1: tw = 1
    float2 p=shflx(v[r],1);
    float sx=(lane&1)?-1.f:1.f;
    v[r]=make_float2(fmaf(sx,v[r].x,p.x), fmaf(sx,v[r].y,p.y));
  }
}

// Inverse DIT: input X[brev8(d)] at slot d; natural output at slot d.
__device__ __forceinline__ void fft256_dit(float2 v[4], int lane, const Tw& T){
#pragma unroll
  for (int r=0;r<4;++r){                       // h=1
    float2 p=shflx(v[r],1);
    float sx=(lane&1)?-1.f:1.f;
    v[r]=make_float2(fmaf(sx,v[r].x,p.x), fmaf(sx,v[r].y,p.y));
  }
#pragma unroll
  for (int r=0;r<4;++r){                       // h=2
    float2 w=v[r];
    if ((lane&3)==3) w=cmulj(w,T.si);
    float2 p=shflx(w,2);
    float sx=(lane&2)?-1.f:1.f;
    v[r]=make_float2(fmaf(sx,w.x,p.x), fmaf(sx,w.y,p.y));
  }
#pragma unroll
  for (int r=0;r<4;++r) v[r]=bfly_dit(v[r],4,T.t4,lane);
#pragma unroll
  for (int r=0;r<4;++r) v[r]=bfly_dit(v[r],8,T.t8,lane);
#pragma unroll
  for (int r=0;r<4;++r) v[r]=bfly_dit(v[r],16,T.t16,lane);
#pragma unroll
  for (int r=0;r<4;++r) v[r]=bfly_dit(v[r],32,T.t32,lane);
  { v[1]=cmul(v[1],T.t64); float2 a=v[0]; v[0]=cadd(a,v[1]); v[1]=csub(a,v[1]);
    v[3]=cmul(v[3],T.t64); float2 c=v[2]; v[2]=cadd(c,v[3]); v[3]=csub(c,v[3]); }
  { v[2]=cmul(v[2],T.t128); v[3]=cmul(v[3], cmulj(T.t128,T.si));
    float2 a=v[0]; v[0]=cadd(a,v[2]); v[2]=csub(a,v[2]);
    float2 b=v[1]; v[1]=cadd(b,v[3]); v[3]=csub(b,v[3]); }
}

// stage row permutation: kw=4q+c -> row 33c+q gives conflict-free scatter banks
__device__ __forceinline__ int stage_row(int kw){ return 33*(kw&3) + (kw>>2); }

// ---------------- Pass 1: row rfft, 2 real rows per complex FFT ----------------
__global__ __launch_bounds__(256) void k_rowfft(const float* __restrict__ x, u32* __restrict__ F) {
  __shared__ u32 stage[131*65];
  const int bc = blockIdx.x >> 2, hc = blockIdx.x & 3;
  const int tid = threadIdx.x, wave = tid >> 6, lane = tid & 63;
  Tw T = make_tw(lane, -1.f);
  const int L = brev6(lane);
  const int laneP0 = brev6((64 - L) & 63);   // partner lane for c=0
  const int lanePX = 63 - lane;              // partner lane for c!=0

  for (int rr = 0; rr < 8; ++rr) {
    const int hl0 = wave*16 + rr*2, hl1 = hl0 + 1;
    const float* xa = x + ((size_t)bc*256 + hc*64 + hl0) * 256;
    float2 v[4];
#pragma unroll
    for (int r=0;r<4;++r){ int d = lane + 64*r; v[r] = make_float2(xa[d], xa[256+d]); }
    fft256_dif(v, lane, T);
    // unscramble Z -> A (row hl0), B (row hl1); keep kw<=128
#define UNSCR(R, RP, C, LP) { \
      float2 z = v[R]; float2 p = shfll(v[RP], LP); \
      float2 A  = make_float2(0.5f*(z.x+p.x), 0.5f*(z.y-p.y)); \
      float2 Bv = make_float2(0.5f*(z.y+p.y), 0.5f*(p.x-z.x)); \
      int kw = 4*L + (C); \
      if (kw <= 128) { int row = stage_row(kw); \
        stage[row*65 + hl0] = pack_bf16(A.x, A.y); \
        stage[row*65 + hl1] = pack_bf16(Bv.x, Bv.y); } }
    UNSCR(0, 0, 0, laneP0)
    UNSCR(1, 1, 2, lanePX)
    UNSCR(2, 3, 1, lanePX)
    UNSCR(3, 2, 3, lanePX)
#undef UNSCR
  }
  __syncthreads();
  for (int idx = tid; idx < 129*64; idx += 256) {
    int kw = idx >> 6, hl = idx & 63;
    F[((size_t)bc*129 + kw)*256 + hc*64 + hl] = stage[stage_row(kw)*65 + hl];
  }
}

// ---------------- Pass 2/4: column FFT (H axis) in registers, scale 1/256 -------
__global__ __launch_bounds__(256) void k_colfft(u32* __restrict__ F, int inverse) {
  const int tid = threadIdx.x, wave = tid >> 6, lane = tid & 63;
  const float si = inverse ? 1.f : -1.f;
  Tw T = make_tw(lane, si);
  u32* p = F + ((size_t)blockIdx.x*4 + wave) * 256;
  float2 v[4];
#pragma unroll
  for (int r=0;r<4;++r) v[r] = unpack_bf16(p[lane + 64*r]);
  if (!inverse) fft256_dif(v, lane, T);
  else          fft256_dit(v, lane, T);
  const float s = 1.0f/256.0f;
#pragma unroll
  for (int r=0;r<4;++r) p[lane + 64*r] = pack_bf16(v[r].x*s, v[r].y*s);
}

// ---------------- Weight prep (unchanged) ----------------
__global__ __launch_bounds__(256) void k_prep_w(const float2* __restrict__ w1,
                                                const float2* __restrict__ w2,
                                                u32* __restrict__ Wt) {
  const int blk = blockIdx.x;      // k*2 + layer
  const int k = blk >> 1, layer = blk & 1;
  const float2* w = (layer == 0 ? w1 : w2) + (size_t)k * 96 * 96;
  u32* out = Wt + (size_t)blk * 18432;
  for (int idx = threadIdx.x; idx < 9216; idx += 256) {
    int o = idx % 96, i = idx / 96;
    float2 v = w[i * 96 + o];
    out[(2 * o) * 96 + i]     = pack_bf16(v.x, -v.y);
    out[(2 * o + 1) * 96 + i] = pack_bf16(v.y, v.x);
  }
}

// ---------------- Pass 3: MFMA block-MLP (unchanged from round 2) ----------------
#define MIX_LDS_BYTES (73728 + 49152)

__global__ __launch_bounds__(512) void k_mix_mfma(u32* __restrict__ F,
    const u32* __restrict__ Wt,
    const float2* __restrict__ b1, const float2* __restrict__ b2) {
  extern __shared__ char smem[];
  char* Wlds = smem;
  char* Dlds = smem + 73728;

  const int bi = blockIdx.x;
  const int hc = bi & 1;
  const int kw = (bi >> 1) % 129;
  const int bk = (bi >> 1) / 129;
  const int k = bk & 7, b = bk >> 3;
  const int t = threadIdx.x;
  const int lane = t & 63, wave = t >> 6;
  const int wm = wave >> 2, wn = wave & 3;
  const int lrow = lane & 15;
  const int lk = (lane >> 4) * 16;

  const u32* W1g = Wt + (size_t)(k * 2 + 0) * 18432;
  const u32* W2g = Wt + (size_t)(k * 2 + 1) * 18432;

#pragma unroll
  for (int c = 0; c < 9; ++c) {
    int idx = c * 512 + t;
    int byte = idx * 16;
    int row = idx / 24;
    uint4 v = reinterpret_cast<const uint4*>(W1g)[idx];
    *reinterpret_cast<uint4*>(Wlds + (byte ^ ((row & 7) << 4))) = v;
  }

  const size_t chstride = 129 * 256;
  const size_t base = (((size_t)(b * 768 + k * 96)) * 129 + kw) * 256 + (size_t)hc * 128;
  {
    const int h = t & 127;
    const int pg = t >> 7;
#pragma unroll
    for (int it = 0; it < 12; ++it) {
      int p = it * 4 + pg;
      u32 a0 = F[base + (size_t)(2 * p) * chstride + h];
      u32 a1 = F[base + (size_t)(2 * p + 1) * chstride + h];
      int byte = h * 384 + p * 8;
      *reinterpret_cast<uint2*>(Dlds + (byte ^ ((h & 7) << 4))) = make_uint2(a0, a1);
    }
  }

  uint4 w2buf[9];
#pragma unroll
  for (int c = 0; c < 9; ++c) w2buf[c] = reinterpret_cast<const uint4*>(W2g)[c * 512 + t];

  __syncthreads();

  f32x4 acc[6][2];
#pragma unroll
  for (int mi = 0; mi < 6; ++mi)
#pragma unroll
    for (int ni = 0; ni < 2; ++ni) acc[mi][ni] = (f32x4)0.f;

#pragma unroll
  for (int ks = 0; ks < 6; ++ks) {
    const int kb = ks * 64;
    bf16x8 afrag[6];
#pragma unroll
    for (int mi = 0; mi < 6; ++mi) {
      int row = wm * 96 + mi * 16 + lrow;
      int byte = row * 384 + kb + lk;
      afrag[mi] = *reinterpret_cast<bf16x8*>(Wlds + (byte ^ ((row & 7) << 4)));
    }
#pragma unroll
    for (int ni = 0; ni < 2; ++ni) {
      int row = wn * 32 + ni * 16 + lrow;
      int byte = row * 384 + kb + lk;
      bf16x8 bfrag = *reinterpret_cast<bf16x8*>(Dlds + (byte ^ ((row & 7) << 4)));
#pragma unroll
      for (int mi = 0; mi < 6; ++mi)
        acc[mi][ni] = __builtin_amdgcn_mfma_f32_16x16x32_bf16(afrag[mi], bfrag, acc[mi][ni], 0, 0, 0);
    }
  }
  __syncthreads();

#pragma unroll
  for (int c = 0; c < 9; ++c) {
    int idx = c * 512 + t;
    int byte = idx * 16;
    int row = idx / 24;
    *reinterpret_cast<uint4*>(Wlds + (byte ^ ((row & 7) << 4))) = w2buf[c];
  }
  const float2* b1k = b1 + k * 96;
#pragma unroll
  for (int mi = 0; mi < 6; ++mi) {
    int m0 = wm * 96 + mi * 16 + 4 * (lane >> 4);
    int o0 = m0 >> 1;
    float2 ba = b1k[o0], bb = b1k[o0 + 1];
#pragma unroll
    for (int ni = 0; ni < 2; ++ni) {
      int n = wn * 32 + ni * 16 + lrow;
      f32x4 v = acc[mi][ni];
      u32 lo  = pack_bf16(fmaxf(v[0] + ba.x, 0.f), fmaxf(v[1] + ba.y, 0.f));
      u32 hi  = pack_bf16(fmaxf(v[2] + bb.x, 0.f), fmaxf(v[3] + bb.y, 0.f));
      int byte = n * 384 + m0 * 2;
      *reinterpret_cast<uint2*>(Dlds + (byte ^ ((n & 7) << 4))) = make_uint2(lo, hi);
    }
  }
  __syncthreads();

#pragma unroll
  for (int mi = 0; mi < 6; ++mi)
#pragma unroll
    for (int ni = 0; ni < 2; ++ni) acc[mi][ni] = (f32x4)0.f;

#pragma unroll
  for (int ks = 0; ks < 6; ++ks) {
    const int kb = ks * 64;
    bf16x8 afrag[6];
#pragma unroll
    for (int mi = 0; mi < 6; ++mi) {
      int row = wm * 96 + mi * 16 + lrow;
      int byte = row * 384 + kb + lk;
      afrag[mi] = *reinterpret_cast<bf16x8*>(Wlds + (byte ^ ((row & 7) << 4)));
    }
#pragma unroll
    for (int ni = 0; ni < 2; ++ni) {
      int row = wn * 32 + ni * 16 + lrow;
      int byte = row * 384 + kb + lk;
      bf16x8 bfrag = *reinterpret_cast<bf16x8*>(Dlds + (byte ^ ((row & 7) << 4)));
#pragma unroll
      for (int mi = 0; mi < 6; ++mi)
        acc[mi][ni] = __builtin_amdgcn_mfma_f32_16x16x32_bf16(afrag[mi], bfrag, acc[mi][ni], 0, 0, 0);
    }
  }

  const float2* b2k = b2 + k * 96;
#pragma unroll
  for (int mi = 0; mi < 6; ++mi) {
    int m0 = wm * 96 + mi * 16 + 4 * (lane >> 4);
    int o0 = m0 >> 1;
    float2 ca = b2k[o0], cb = b2k[o0 + 1];
#pragma unroll
    for (int ni = 0; ni < 2; ++ni) {
      int n = wn * 32 + ni * 16 + lrow;
      f32x4 v = acc[mi][ni];
      u32 lo = pack_bf16(sshrink(v[0] + ca.x), sshrink(v[1] + ca.y));
      u32 hi = pack_bf16(sshrink(v[2] + cb.x), sshrink(v[3] + cb.y));
      F[base + (size_t)o0 * chstride + n]       = lo;
      F[base + (size_t)(o0 + 1) * chstride + n] = hi;
    }
  }
}

// ---------------- Pass 5: row irfft (Hermitian ext), 2 rows per FFT, + bias ------
__global__ __launch_bounds__(256) void k_rowifft(const u32* __restrict__ F,
                                                 const float* __restrict__ x,
                                                 float* __restrict__ out) {
  __shared__ u32 stage[131*65];
  const int bc = blockIdx.x >> 2, hc = blockIdx.x & 3;
  const int tid = threadIdx.x, wave = tid >> 6, lane = tid & 63;
  Tw T = make_tw(lane, 1.f);
  for (int idx = tid; idx < 129*64; idx += 256) {
    int kw = idx >> 6, hl = idx & 63;
    stage[stage_row(kw)*65 + hl] = F[((size_t)bc*129 + kw)*256 + hc*64 + hl];
  }
  __syncthreads();

  const int L = brev6(lane);
  for (int rr = 0; rr < 8; ++rr) {
    const int hl0 = wave*16 + rr*2, hl1 = hl0 + 1;
    float2 v[4];
#pragma unroll
    for (int r=0;r<4;++r) {
      int c = ((r&1)<<1) | (r>>1);           // brev2(r)
      int kw = 4*L + c;                      // 0..255
      int src = (kw <= 128) ? kw : 256 - kw;
      float sg = (kw <= 128) ? 1.f : -1.f;
      int row = stage_row(src);
      float2 a = unpack_bf16(stage[row*65 + hl0]);
      float2 b = unpack_bf16(stage[row*65 + hl1]);
      a.y *= sg; b.y *= sg;
      if (kw == 0 || kw == 128) { a.y = 0.f; b.y = 0.f; }
      v[r] = make_float2(a.x - b.y, a.y + b.x);   // A + i*B
    }
    fft256_dit(v, lane, T);
    const float* xa = x   + ((size_t)bc*256 + hc*64 + hl0) * 256;
    float*       oa = out + ((size_t)bc*256 + hc*64 + hl0) * 256;
#pragma unroll
    for (int r=0;r<4;++r) {
      int d = lane + 64*r;
      oa[d]       = v[r].x + xa[d];
      oa[256 + d] = v[r].y + xa[256 + d];
    }
  }
}

extern "C" void kernel_launch(void* const* d_in, const int* in_sizes, int n_in,
                              void* d_out, int out_size, void* d_ws, size_t ws_size,
                              hipStream_t stream) {
  const float* x   = (const float*)d_in[0];
  const float2* w1 = (const float2*)d_in[1];
  const float2* b1 = (const float2*)d_in[2];
  const float2* w2 = (const float2*)d_in[3];
  const float2* b2 = (const float2*)d_in[4];
  float* out = (float*)d_out;
  u32* F = (u32*)d_ws;            // 1536*129*256*4 B ~ 203 MB
  u32* Wt = (u32*)d_out;          // d_out head as scratch; overwritten by k_rowifft

  (void)hipFuncSetAttribute(reinterpret_cast<const void*>(k_mix_mfma),
                            hipFuncAttributeMaxDynamicSharedMemorySize, MIX_LDS_BYTES);

  const int n_rows_blocks = 1536 * 4;
  const int n_cols_blocks = (1536 * 129) / 4;
  const int n_mix_blocks  = 2 * 8 * 129 * 2;

  k_prep_w<<<16, 256, 0, stream>>>(w1, w2, Wt);
  k_rowfft<<<n_rows_blocks, 256, 0, stream>>>(x, F);
  k_colfft<<<n_cols_blocks, 256, 0, stream>>>(F, 0);
  k_mix_mfma<<<n_mix_blocks, 512, MIX_LDS_BYTES, stream>>>(F, Wt, b1, b2);
  k_colfft<<<n_cols_blocks, 256, 0, stream>>>(F, 1);
  k_rowifft<<<n_rows_blocks, 256, 0, stream>>>(F, x, out);
}